// Round 7
// baseline (183.124 us; speedup 1.0000x reference)
//
#include <hip/hip_runtime.h>
#include <math.h>

#define R 1000
#define NC 81
#define CAP 1024       // >= R, so compaction can never overflow
#define NT 512
#define NWAVE (NT / 64)
#define SUPMAX 512     // matrix-NMS path handles V <= SUPMAX
#define WMAX 8         // SUPMAX / 64 keep-words

// Single fused kernel: one block per class (80 blocks).
// Redundant per-block softmax is deliberate: only 80 blocks on 256 CUs, and
// wave-per-row layout makes the score reads coalesced + L2-shared across all
// blocks. This removes the stats kernel, the scatter kernel, and the memset
// node -> 1 graph node instead of 3 (each node/dependency cost ~5-10 us).
__global__ __launch_bounds__(NT) void frcnn_fused_kernel(
    const float* __restrict__ roi,        // [R,4]  (ymin,xmin,ymax,xmax)
    const float* __restrict__ roi_loc,    // [R, NC*4]
    const float* __restrict__ roi_score,  // [R, NC]
    float* __restrict__ out)              // [80*R*5] boxes+score, then [80*R] labels
{
    const int c    = blockIdx.x + 1;      // class 1..80
    const int tid  = threadIdx.x;
    const int wid  = tid >> 6;
    const int lane = tid & 63;

    __shared__ float s_score[CAP];        // compacted (unsorted) probs
    __shared__ int   s_idx[CAP];          // compacted (unsorted) roi indices
    __shared__ float s_ss[CAP];           // sorted score
    __shared__ float s_y0[CAP], s_x0[CAP], s_y1[CAP], s_x1[CAP], s_area[CAP];
    __shared__ int   s_keepi[CAP];        // fallback path only
    __shared__ unsigned long long s_sup[SUPMAX * WMAX];
    __shared__ unsigned long long s_kw[WMAX];
    __shared__ int   s_cnt;

    if (tid == 0) s_cnt = 0;
    __syncthreads();

    // ---- 1. wave-per-row softmax; compact (p > 0.05) into LDS ----
    // lane = class -> coalesced row loads; butterfly reduce; shfl out class c.
    for (int r = wid; r < R; r += NWAVE) {
        const float* sc = roi_score + r * NC;
        float v0 = sc[lane];
        float v1 = (lane < NC - 64) ? sc[lane + 64] : -INFINITY;
        float m = fmaxf(v0, v1);
        #pragma unroll
        for (int off = 32; off > 0; off >>= 1)
            m = fmaxf(m, __shfl_xor(m, off, 64));
        float e = expf(v0 - m) + ((lane < NC - 64) ? expf(v1 - m) : 0.0f);
        #pragma unroll
        for (int off = 32; off > 0; off >>= 1)
            e += __shfl_xor(e, off, 64);
        float scc = (c < 64) ? __shfl(v0, c, 64) : __shfl(v1, c - 64, 64);
        float p = expf(scc - m) / e;
        if (lane == 0 && p > 0.05f) {
            int slot = atomicAdd(&s_cnt, 1);    // LDS atomic, cheap
            s_score[slot] = p;
            s_idx[slot]   = r;
        }
    }
    __syncthreads();
    const int V = s_cnt;

    // ---- 2. rank-sort (stable argsort by (-score, idx)) + fused decode ----
    // rank[p] = #{q : (s_q > s_p) || (s_q == s_p && idx_q < idx_p)}
    // all threads stream the same q together -> LDS broadcast, conflict-free
    for (int p = tid; p < V; p += NT) {
        float sp = s_score[p];
        int   ip = s_idx[p];
        int rank = 0;
        for (int q = 0; q < V; ++q) {
            float sq = s_score[q];
            int   iq = s_idx[q];
            rank += (sq > sp) || (sq == sp && iq < ip);
        }
        // decode + clamp box for roi ip, write straight to sorted slot
        float ry0 = roi[ip*4+0], rx0 = roi[ip*4+1];
        float ry1 = roi[ip*4+2], rx1 = roi[ip*4+3];
        float h = ry1 - ry0, w = rx1 - rx0;
        float cy = ry0 + 0.5f*h, cx = rx0 + 0.5f*w;
        const float* lp = roi_loc + (size_t)ip*(NC*4) + c*4;
        float dy = lp[0]*0.1f, dx = lp[1]*0.1f;
        float dh = lp[2]*0.2f, dw = lp[3]*0.2f;
        float ny = dy*h + cy, nx = dx*w + cx;
        float nh = expf(dh)*h, nw = expf(dw)*w;
        float y0 = ny - 0.5f*nh, x0 = nx - 0.5f*nw;
        float y1 = ny + 0.5f*nh, x1 = nx + 0.5f*nw;
        y0 = fminf(fmaxf(y0, 0.f), 600.f);
        x0 = fminf(fmaxf(x0, 0.f), 800.f);
        y1 = fminf(fmaxf(y1, 0.f), 600.f);
        x1 = fminf(fmaxf(x1, 0.f), 800.f);
        s_ss[rank] = sp;
        s_y0[rank] = y0; s_x0[rank] = x0; s_y1[rank] = y1; s_x1[rank] = x1;
        s_area[rank] = (y1 - y0) * (x1 - x0);
        s_keepi[rank] = 1;
    }
    __syncthreads();

    // ---- 3. NMS ----
    if (V > 0 && V <= SUPMAX) {
        const int W = (V + 63) >> 6;
        // 3a. suppression bit-matrix, one row per thread
        for (int i = tid; i < V; i += NT) {
            float ay0 = s_y0[i], ax0 = s_x0[i];
            float ay1 = s_y1[i], ax1 = s_x1[i];
            float aa  = s_area[i];
            for (int w = 0; w < W; ++w) {
                int j0 = w * 64;
                int js = (i + 1 > j0) ? i + 1 : j0;
                int je = (j0 + 64 < V) ? j0 + 64 : V;
                unsigned long long bits = 0ull;
                for (int j = js; j < je; ++j) {
                    float ty = fmaxf(ay0, s_y0[j]);
                    float tx = fmaxf(ax0, s_x0[j]);
                    float by = fminf(ay1, s_y1[j]);
                    float bx = fminf(ax1, s_x1[j]);
                    float hh = fmaxf(by - ty, 0.f);
                    float ww = fmaxf(bx - tx, 0.f);
                    float inter = hh * ww;
                    float iou = inter / (aa + s_area[j] - inter + 1e-9f);
                    if (iou > 0.5f) bits |= (1ull << (j - j0));
                }
                s_sup[i * W + w] = bits;
            }
        }
        __syncthreads();
        // 3b. serial scan, keep-words held in thread-0 REGISTERS
        if (tid == 0) {
            unsigned long long kw[WMAX];
            #pragma unroll
            for (int w = 0; w < WMAX; ++w) {
                int full = V - w * 64;
                kw[w] = (full >= 64) ? ~0ull : (full > 0 ? ((1ull << full) - 1ull) : 0ull);
            }
            #pragma unroll
            for (int w = 0; w < WMAX; ++w) {
                if (w * 64 < V) {
                    unsigned long long cur = kw[w];
                    int lim = V - w * 64; if (lim > 64) lim = 64;
                    for (int b = 0; b < lim; ++b) {
                        if ((cur >> b) & 1ull) {
                            const unsigned long long* row = &s_sup[(w * 64 + b) * W];
                            cur &= ~row[w];
                            #pragma unroll
                            for (int w2 = 0; w2 < WMAX; ++w2) {
                                if (w2 > w) { if (w2 < W) kw[w2] &= ~row[w2]; }
                            }
                        }
                    }
                    kw[w] = cur;
                }
            }
            #pragma unroll
            for (int w = 0; w < WMAX; ++w) s_kw[w] = kw[w];
        }
        __syncthreads();
    } else if (V > SUPMAX) {
        // fallback: sequential-i / parallel-j greedy (correct for any V)
        for (int i = 0; i < V; ++i) {
            if (s_keepi[i]) {
                float ay0 = s_y0[i], ax0 = s_x0[i];
                float ay1 = s_y1[i], ax1 = s_x1[i];
                float aa  = s_area[i];
                for (int jj = i + 1 + tid; jj < V; jj += NT) {
                    float ty = fmaxf(ay0, s_y0[jj]);
                    float tx = fmaxf(ax0, s_x0[jj]);
                    float by = fminf(ay1, s_y1[jj]);
                    float bx = fminf(ax1, s_x1[jj]);
                    float hh = fmaxf(by - ty, 0.f);
                    float ww = fmaxf(bx - tx, 0.f);
                    float inter = hh * ww;
                    float iou = inter / (aa + s_area[jj] - inter + 1e-9f);
                    if (iou > 0.5f) s_keepi[jj] = 0;
                }
            }
            __syncthreads();
        }
    }

    // ---- 4. write outputs (covers full buffer; no memset needed) ----
    const bool matrix_path = (V <= SUPMAX);
    float* out0 = out + (size_t)(c - 1) * R * 5;
    float* out1 = out + (size_t)80 * R * 5 + (size_t)(c - 1) * R;
    for (int p = tid; p < R; p += NT) {
        bool kept = false;
        if (p < V)
            kept = matrix_path ? (((s_kw[p >> 6] >> (p & 63)) & 1ull) != 0ull)
                               : (s_keepi[p] != 0);
        float y0 = 0.f, x0 = 0.f, y1 = 0.f, x1 = 0.f, s = 0.f, lab = -1.0f;
        if (kept) {
            y0 = s_y0[p]; x0 = s_x0[p]; y1 = s_y1[p]; x1 = s_x1[p];
            s  = s_ss[p];
            lab = (float)(c - 1);
        }
        out0[p*5+0] = y0; out0[p*5+1] = x0; out0[p*5+2] = y1;
        out0[p*5+3] = x1; out0[p*5+4] = s;
        out1[p] = lab;
    }
}

extern "C" void kernel_launch(void* const* d_in, const int* in_sizes, int n_in,
                              void* d_out, int out_size, void* d_ws, size_t ws_size,
                              hipStream_t stream) {
    const float* roi       = (const float*)d_in[0];
    const float* roi_loc   = (const float*)d_in[1];
    const float* roi_score = (const float*)d_in[2];
    float* out = (float*)d_out;

    hipLaunchKernelGGL(frcnn_fused_kernel, dim3(NC - 1), dim3(NT), 0, stream,
                       roi, roi_loc, roi_score, out);
}

// Round 8
// 86.740 us; speedup vs baseline: 2.1112x; 2.1112x over previous
//
#include <hip/hip_runtime.h>
#include <math.h>

#define R 1000
#define NC 81
#define CAP 1024       // >= R, so compaction can never overflow
#define NT 512         // kernel B block size
#define SUPMAX 512     // matrix-NMS path handles V <= SUPMAX
#define WMAX 8         // SUPMAX / 64 keep-words
#define PT_LD 1024     // probT leading dim (padded 1000 -> 1024)

// ---- Kernel A: wave-per-RoI softmax -> transposed prob matrix -------------
// 1000 waves (250 blocks x 4 waves), one RoI each: max parallelism so the
// ~700-cycle shfl-reduce dependent chain is fully latency-hidden (R7 lesson:
// the same math at 2 waves/SIMD costs 135us). Writes probT[class][roi] so
// kernel B's per-class read is a contiguous 4KB segment.
__global__ __launch_bounds__(256) void softmax_probT_kernel(
    const float* __restrict__ roi_score,  // [R, NC]
    float* __restrict__ probT)            // [NC * PT_LD]
{
    const int wid  = threadIdx.x >> 6;
    const int lane = threadIdx.x & 63;
    const int r    = blockIdx.x * 4 + wid;
    if (r >= R) return;
    const float* sc = roi_score + r * NC;
    float v0 = sc[lane];
    float v1 = (lane < NC - 64) ? sc[lane + 64] : -INFINITY;
    float m = fmaxf(v0, v1);
    #pragma unroll
    for (int off = 32; off > 0; off >>= 1)
        m = fmaxf(m, __shfl_xor(m, off, 64));
    float e0 = expf(v0 - m);
    float e1 = (lane < NC - 64) ? expf(v1 - m) : 0.0f;
    float e = e0 + e1;
    #pragma unroll
    for (int off = 32; off > 0; off >>= 1)
        e += __shfl_xor(e, off, 64);
    float rcp = 1.0f / e;
    probT[lane * PT_LD + r] = e0 * rcp;              // class = lane (0..63)
    if (lane < NC - 64)
        probT[(lane + 64) * PT_LD + r] = e1 * rcp;   // class = lane+64 (64..80)
}

// ---- Kernel B: per-class compact + rank-sort + decode + NMS + write -------
__global__ __launch_bounds__(NT) void frcnn_class_kernel(
    const float* __restrict__ roi,        // [R,4]
    const float* __restrict__ roi_loc,    // [R, NC*4]
    const float* __restrict__ probT,      // [NC * PT_LD]
    float* __restrict__ out)              // [80*R*5] boxes+score, then [80*R] labels
{
    const int c   = blockIdx.x + 1;       // class 1..80
    const int tid = threadIdx.x;

    __shared__ float s_score[CAP];        // compacted (unsorted) probs
    __shared__ int   s_idx[CAP];          // compacted (unsorted) roi indices
    __shared__ float s_ss[CAP];           // sorted score
    __shared__ float s_y0[CAP], s_x0[CAP], s_y1[CAP], s_x1[CAP], s_area[CAP];
    __shared__ int   s_keepi[CAP];        // fallback path only
    __shared__ unsigned long long s_sup[SUPMAX * WMAX];
    __shared__ unsigned long long s_kw[WMAX];
    __shared__ int   s_cnt;

    if (tid == 0) s_cnt = 0;
    __syncthreads();

    // ---- 1. compact valid (p > 0.05): coalesced contiguous read ----
    const float* pc = probT + c * PT_LD;
    for (int r = tid; r < R; r += NT) {
        float p = pc[r];
        if (p > 0.05f) {
            int slot = atomicAdd(&s_cnt, 1);
            s_score[slot] = p;
            s_idx[slot]   = r;
        }
    }
    __syncthreads();
    const int V = s_cnt;

    // ---- 2. rank-sort (stable argsort by (-score, idx)) + fused decode ----
    for (int p = tid; p < V; p += NT) {
        float sp = s_score[p];
        int   ip = s_idx[p];
        int rank = 0;
        for (int q = 0; q < V; ++q) {
            float sq = s_score[q];
            int   iq = s_idx[q];
            rank += (sq > sp) || (sq == sp && iq < ip);
        }
        float ry0 = roi[ip*4+0], rx0 = roi[ip*4+1];
        float ry1 = roi[ip*4+2], rx1 = roi[ip*4+3];
        float h = ry1 - ry0, w = rx1 - rx0;
        float cy = ry0 + 0.5f*h, cx = rx0 + 0.5f*w;
        const float* lp = roi_loc + (size_t)ip*(NC*4) + c*4;
        float dy = lp[0]*0.1f, dx = lp[1]*0.1f;
        float dh = lp[2]*0.2f, dw = lp[3]*0.2f;
        float ny = dy*h + cy, nx = dx*w + cx;
        float nh = expf(dh)*h, nw = expf(dw)*w;
        float y0 = ny - 0.5f*nh, x0 = nx - 0.5f*nw;
        float y1 = ny + 0.5f*nh, x1 = nx + 0.5f*nw;
        y0 = fminf(fmaxf(y0, 0.f), 600.f);
        x0 = fminf(fmaxf(x0, 0.f), 800.f);
        y1 = fminf(fmaxf(y1, 0.f), 600.f);
        x1 = fminf(fmaxf(x1, 0.f), 800.f);
        s_ss[rank] = sp;
        s_y0[rank] = y0; s_x0[rank] = x0; s_y1[rank] = y1; s_x1[rank] = x1;
        s_area[rank] = (y1 - y0) * (x1 - x0);
        s_keepi[rank] = 1;
    }
    __syncthreads();

    // ---- 3. NMS ----
    if (V > 0 && V <= SUPMAX) {
        const int W = (V + 63) >> 6;
        // 3a. suppression bit-matrix, one row per thread
        for (int i = tid; i < V; i += NT) {
            float ay0 = s_y0[i], ax0 = s_x0[i];
            float ay1 = s_y1[i], ax1 = s_x1[i];
            float aa  = s_area[i];
            for (int w = 0; w < W; ++w) {
                int j0 = w * 64;
                int js = (i + 1 > j0) ? i + 1 : j0;
                int je = (j0 + 64 < V) ? j0 + 64 : V;
                unsigned long long bits = 0ull;
                for (int j = js; j < je; ++j) {
                    float ty = fmaxf(ay0, s_y0[j]);
                    float tx = fmaxf(ax0, s_x0[j]);
                    float by = fminf(ay1, s_y1[j]);
                    float bx = fminf(ax1, s_x1[j]);
                    float hh = fmaxf(by - ty, 0.f);
                    float ww = fmaxf(bx - tx, 0.f);
                    float inter = hh * ww;
                    float iou = inter / (aa + s_area[j] - inter + 1e-9f);
                    if (iou > 0.5f) bits |= (1ull << (j - j0));
                }
                s_sup[i * W + w] = bits;
            }
        }
        __syncthreads();
        // 3b. serial scan, keep-words held in thread-0 registers
        if (tid == 0) {
            unsigned long long kw[WMAX];
            #pragma unroll
            for (int w = 0; w < WMAX; ++w) {
                int full = V - w * 64;
                kw[w] = (full >= 64) ? ~0ull : (full > 0 ? ((1ull << full) - 1ull) : 0ull);
            }
            #pragma unroll
            for (int w = 0; w < WMAX; ++w) {
                if (w * 64 < V) {
                    unsigned long long cur = kw[w];
                    int lim = V - w * 64; if (lim > 64) lim = 64;
                    for (int b = 0; b < lim; ++b) {
                        if ((cur >> b) & 1ull) {
                            const unsigned long long* row = &s_sup[(w * 64 + b) * W];
                            cur &= ~row[w];
                            #pragma unroll
                            for (int w2 = 0; w2 < WMAX; ++w2) {
                                if (w2 > w) { if (w2 < W) kw[w2] &= ~row[w2]; }
                            }
                        }
                    }
                    kw[w] = cur;
                }
            }
            #pragma unroll
            for (int w = 0; w < WMAX; ++w) s_kw[w] = kw[w];
        }
        __syncthreads();
    } else if (V > SUPMAX) {
        // fallback: sequential-i / parallel-j greedy (correct for any V)
        for (int i = 0; i < V; ++i) {
            if (s_keepi[i]) {
                float ay0 = s_y0[i], ax0 = s_x0[i];
                float ay1 = s_y1[i], ax1 = s_x1[i];
                float aa  = s_area[i];
                for (int jj = i + 1 + tid; jj < V; jj += NT) {
                    float ty = fmaxf(ay0, s_y0[jj]);
                    float tx = fmaxf(ax0, s_x0[jj]);
                    float by = fminf(ay1, s_y1[jj]);
                    float bx = fminf(ax1, s_x1[jj]);
                    float hh = fmaxf(by - ty, 0.f);
                    float ww = fmaxf(bx - tx, 0.f);
                    float inter = hh * ww;
                    float iou = inter / (aa + s_area[jj] - inter + 1e-9f);
                    if (iou > 0.5f) s_keepi[jj] = 0;
                }
            }
            __syncthreads();
        }
    }

    // ---- 4. write outputs (covers full buffer; no memset needed) ----
    const bool matrix_path = (V <= SUPMAX);
    float* out0 = out + (size_t)(c - 1) * R * 5;
    float* out1 = out + (size_t)80 * R * 5 + (size_t)(c - 1) * R;
    for (int p = tid; p < R; p += NT) {
        bool kept = false;
        if (p < V)
            kept = matrix_path ? (((s_kw[p >> 6] >> (p & 63)) & 1ull) != 0ull)
                               : (s_keepi[p] != 0);
        float y0 = 0.f, x0 = 0.f, y1 = 0.f, x1 = 0.f, s = 0.f, lab = -1.0f;
        if (kept) {
            y0 = s_y0[p]; x0 = s_x0[p]; y1 = s_y1[p]; x1 = s_x1[p];
            s  = s_ss[p];
            lab = (float)(c - 1);
        }
        out0[p*5+0] = y0; out0[p*5+1] = x0; out0[p*5+2] = y1;
        out0[p*5+3] = x1; out0[p*5+4] = s;
        out1[p] = lab;
    }
}

extern "C" void kernel_launch(void* const* d_in, const int* in_sizes, int n_in,
                              void* d_out, int out_size, void* d_ws, size_t ws_size,
                              hipStream_t stream) {
    const float* roi       = (const float*)d_in[0];
    const float* roi_loc   = (const float*)d_in[1];
    const float* roi_score = (const float*)d_in[2];
    float* out   = (float*)d_out;
    float* probT = (float*)d_ws;          // [NC * PT_LD] = 332 KB

    hipLaunchKernelGGL(softmax_probT_kernel, dim3((R + 3) / 4), dim3(256), 0, stream,
                       roi_score, probT);
    hipLaunchKernelGGL(frcnn_class_kernel, dim3(NC - 1), dim3(NT), 0, stream,
                       roi, roi_loc, probT, out);
}